// Round 9
// baseline (108.343 us; speedup 1.0000x reference)
//
#include <hip/hip_runtime.h>
#include <cstdint>
#include <cstddef>

constexpr int O_C   = 16;     // objects per image
constexpr int P_MAX = 8732;   // priors
constexpr int CH    = 4;      // match chunks per batch
constexpr int CHP   = 2183;   // priors per chunk (4*2183 = 8732)
constexpr int NCE   = 2048;   // persistent CE blocks

__device__ __forceinline__ float waveSumF(float v) {
    #pragma unroll
    for (int off = 32; off; off >>= 1) v += __shfl_xor(v, off);
    return v;
}
__device__ __forceinline__ int waveSumI(int v) {
    #pragma unroll
    for (int off = 32; off; off >>= 1) v += __shfl_xor(v, off);
    return v;
}

// async global -> LDS, 16B per lane (dest = wave-uniform base + lane*16)
__device__ __forceinline__ void async_g2l16(const float* g, float* l) {
    __builtin_amdgcn_global_load_lds(
        (const __attribute__((address_space(1))) void*)g,
        (__attribute__((address_space(3))) void*)l,
        16, 0, 0);
}

// ---------------------------------------------------------------------------
// K1: blocks [0, nmatch)           : per-batch-chunk match -> okey_part only
//     blocks [nmatch, nmatch+NCE)  : persistent LSE over 64-row tiles,
//                                    double-buffered async LDS staging.
// ---------------------------------------------------------------------------
__global__ __launch_bounds__(256) void lse_match(
    const float* __restrict__ confs,          // [rows,81]
    const float* __restrict__ target_boxes,   // [B,O,4] xyxy
    const float* __restrict__ priors,         // [P,4] cxcywh
    unsigned long long* __restrict__ okey_part, // [nmatch*O]
    float* __restrict__ lse_out,              // [rows]
    int P, int ntile, int nmatch)
{
    const int tid  = threadIdx.x;
    const int lane = tid & 63;
    const int wid  = tid >> 6;

    __shared__ __align__(16) float s_t[2][5188];   // 2 x (64*81 + pad)
    __shared__ float bx0[O_C], by0[O_C], bx1[O_C], by1[O_C], barea[O_C];
    __shared__ unsigned long long s_wb[O_C * 4];

    if (blockIdx.x < (unsigned)nmatch) {
        // ---------------- match chunk: per-object best-prior candidates ----
        const int chunk = blockIdx.x;
        const int b = chunk / CH;
        const int c = chunk % CH;

        if (tid < O_C) {
            const float* tb = target_boxes + ((size_t)b * O_C + tid) * 4;
            float x0 = tb[0], y0 = tb[1], x1 = tb[2], y1 = tb[3];
            bx0[tid] = x0; by0[tid] = y0; bx1[tid] = x1; by1[tid] = y1;
            barea[tid] = (x1 - x0) * (y1 - y0);
        }
        __syncthreads();

        float bi[O_C]; int bp[O_C];
        #pragma unroll
        for (int o = 0; o < O_C; ++o) { bi[o] = -1.0f; bp[o] = 0; }

        const int p0 = c * CHP, p1 = min(p0 + CHP, P);
        for (int p = p0 + tid; p < p1; p += 256) {
            float4 pr = reinterpret_cast<const float4*>(priors)[p];
            float px0 = pr.x - pr.z * 0.5f, py0 = pr.y - pr.w * 0.5f;
            float px1 = pr.x + pr.z * 0.5f, py1 = pr.y + pr.w * 0.5f;
            float parea = (px1 - px0) * (py1 - py0);
            #pragma unroll
            for (int o = 0; o < O_C; ++o) {
                float ix0 = fmaxf(px0, bx0[o]), iy0 = fmaxf(py0, by0[o]);
                float ix1 = fminf(px1, bx1[o]), iy1 = fminf(py1, by1[o]);
                float iw = fmaxf(ix1 - ix0, 0.0f), ih = fmaxf(iy1 - iy0, 0.0f);
                float inter = iw * ih;
                float iou = inter / (barea[o] + parea - inter);
                if (iou > bi[o]) { bi[o] = iou; bp[o] = p; } // strict > -> smallest p
            }
        }

        #pragma unroll
        for (int o = 0; o < O_C; ++o) {
            unsigned long long k = (bi[o] >= 0.0f)
                ? (((unsigned long long)__float_as_uint(bi[o]) << 32) |
                   (unsigned long long)(0xFFFFFFFFu - (unsigned)bp[o]))
                : 0ull;
            #pragma unroll
            for (int off = 32; off; off >>= 1) {
                unsigned long long k2 = __shfl_xor(k, off);
                if (k2 > k) k = k2;
            }
            if (lane == 0) s_wb[o * 4 + wid] = k;
        }
        __syncthreads();
        if (tid < O_C) {
            unsigned long long k = s_wb[tid * 4];
            #pragma unroll
            for (int w = 1; w < 4; ++w) if (s_wb[tid * 4 + w] > k) k = s_wb[tid * 4 + w];
            okey_part[(size_t)chunk * O_C + tid] = k;
        }
        return;
    }

    // ---------------- persistent LSE tiles ----------------
    const int bt0 = blockIdx.x - nmatch;
    const int rl = tid >> 2;              // tile-local row 0..63
    const int q  = tid & 3;
    const int s0 = q ? (q * 20 + 1) : 0;  // 0,21,41,61
    const int n  = q ? 20 : 21;

    // stage tile t into buffer buf (async except 16-f4 tail)
    auto stage = [&](int buf, int t) {
        const float* src = confs + (size_t)t * 5184;
        #pragma unroll
        for (int c = 0; c < 5; ++c) {
            // per-lane gsrc; LDS base wave-uniform (HW adds lane*16)
            async_g2l16(src + (size_t)(c * 256 + tid) * 4,
                        &s_t[buf][(c * 256 + wid * 64) * 4]);
        }
        if (tid < 16) {   // tail: float4 1280..1295, sync load + ds_write
            float4 v = reinterpret_cast<const float4*>(src)[1280 + tid];
            reinterpret_cast<float4*>(&s_t[buf][5120])[tid] = v;
        }
    };

    if (bt0 >= ntile) return;
    stage(0, bt0);
    __syncthreads();   // drain prologue

    for (int t = bt0, k = 0; t < ntile; t += NCE, ++k) {
        const int cur = k & 1;
        const int tn = t + NCE;
        if (tn < ntile) stage(cur ^ 1, tn);   // async prefetch overlaps compute

        const float* xr = &s_t[cur][rl * 81];
        float v[21];
        #pragma unroll
        for (int i = 0; i < 21; ++i)
            v[i] = (i < n) ? xr[s0 + i] : -3.0e38f;

        float m = v[0];
        #pragma unroll
        for (int i = 1; i < 21; ++i) m = fmaxf(m, v[i]);
        m = fmaxf(m, __shfl_xor(m, 1));
        m = fmaxf(m, __shfl_xor(m, 2));

        float s = 0.0f;
        #pragma unroll
        for (int i = 0; i < 21; ++i)
            if (i < n) s += __expf(v[i] - m);
        s += __shfl_xor(s, 1);
        s += __shfl_xor(s, 2);

        if (q == 0)
            lse_out[(size_t)t * 64 + rl] = m + __logf(s);

        __syncthreads();   // drain prefetch + protect buffer reuse
    }
}

// ---------------------------------------------------------------------------
// K2 hard: per-batch block. Recomputes per-prior IoU argmax (bit-identical
// to match arithmetic), applies forced-match override, ce = lse - x[label],
// pos sums / n_pos / loc loss, exact top-K negative sum via radix select.
// ---------------------------------------------------------------------------
__global__ __launch_bounds__(1024) void hard_kernel(
    const float* __restrict__ confs,          // [rows,81]
    const float* __restrict__ lse,            // [rows]
    const unsigned long long* __restrict__ okey_part, // [B*CH*O]
    const float* __restrict__ target_boxes,   // [B,O,4]
    const int*   __restrict__ target_labels,  // [B,O]
    const float* __restrict__ priors,         // [P,4]
    const float* __restrict__ predict_locs,   // [B,P,4]
    int*   __restrict__ n_pos,                // [B]
    float* __restrict__ ce_pos,               // [B]
    float* __restrict__ ce_hard,              // [B]
    float* __restrict__ loc_b,                // [B]
    int P)
{
    const int b    = blockIdx.x;
    const int tid  = threadIdx.x;
    const int lane = tid & 63;
    const int wid  = tid >> 6;

    __shared__ float s_v[P_MAX];
    __shared__ unsigned int hist[16][256];
    __shared__ float4 tbox[O_C];
    __shared__ float  tarea[O_C];
    __shared__ int    tlab[O_C], topr[O_C];
    __shared__ unsigned int s_sel;
    __shared__ int s_kr;
    __shared__ float s_f[16], s_f2[16], s_f3[16];
    __shared__ int s_i[16];

    if (tid < O_C) {
        const float* tb = target_boxes + ((size_t)b * O_C + tid) * 4;
        float x0 = tb[0], y0 = tb[1], x1 = tb[2], y1 = tb[3];
        tbox[tid]  = make_float4(x0, y0, x1, y1);
        tarea[tid] = (x1 - x0) * (y1 - y0);
        tlab[tid]  = target_labels[(size_t)b * O_C + tid];
        unsigned long long kk = 0ull;
        #pragma unroll
        for (int cc = 0; cc < CH; ++cc) {
            unsigned long long k2 = okey_part[((size_t)b * CH + cc) * O_C + tid];
            if (k2 > kk) kk = k2;
        }
        topr[tid] = (int)(0xFFFFFFFFu - (unsigned)(kk & 0xFFFFFFFFull));
    }
    __syncthreads();

    const size_t base = (size_t)b * P;
    float possum = 0.0f, negsum = 0.0f, locsum = 0.0f;
    int cnt = 0;
    for (int p = tid; p < P; p += 1024) {
        // recompute per-prior IoU argmax (identical ops/order as match)
        float4 pr = reinterpret_cast<const float4*>(priors)[p];
        float px0 = pr.x - pr.z * 0.5f, py0 = pr.y - pr.w * 0.5f;
        float px1 = pr.x + pr.z * 0.5f, py1 = pr.y + pr.w * 0.5f;
        float parea = (px1 - px0) * (py1 - py0);
        float bv = -1.0f; int bo = 0;
        #pragma unroll
        for (int o = 0; o < O_C; ++o) {
            float4 tb = tbox[o];
            float ix0 = fmaxf(px0, tb.x), iy0 = fmaxf(py0, tb.y);
            float ix1 = fminf(px1, tb.z), iy1 = fminf(py1, tb.w);
            float iw = fmaxf(ix1 - ix0, 0.0f), ih = fmaxf(iy1 - iy0, 0.0f);
            float inter = iw * ih;
            float iou = inter / (tarea[o] + parea - inter);
            if (iou > bv) { bv = iou; bo = o; }   // first-max (argmax over o)
        }
        float ovv = bv;
        int   obj = bo;
        #pragma unroll
        for (int o = 0; o < O_C; ++o)             // ascending -> last write wins
            if (topr[o] == p) { obj = o; ovv = 1.0f; }
        const int l = (ovv < 0.5f) ? 0 : tlab[obj];

        float xl  = confs[(base + p) * 81 + l];
        float cev = lse[base + p] - xl;
        if (l != 0) {
            possum += cev; ++cnt;
            s_v[p] = 0.0f;
            float4 tb = tbox[obj];
            float cx = (tb.x + tb.z) * 0.5f, cy = (tb.y + tb.w) * 0.5f;
            float w  = tb.z - tb.x,          h  = tb.w - tb.y;
            float g0 = (cx - pr.x) / (pr.z * 0.1f);
            float g1 = (cy - pr.y) / (pr.w * 0.1f);
            float g2 = logf(w / pr.z) / 0.2f;
            float g3 = logf(h / pr.w) / 0.2f;
            float4 pl = reinterpret_cast<const float4*>(predict_locs)[base + p];
            locsum += fabsf(pl.x - g0) + fabsf(pl.y - g1) +
                      fabsf(pl.z - g2) + fabsf(pl.w - g3);
        } else {
            negsum += cev;
            s_v[p] = cev;
        }
    }
    possum = waveSumF(possum);
    negsum = waveSumF(negsum);
    locsum = waveSumF(locsum);
    cnt    = waveSumI(cnt);
    if (lane == 0) { s_f[wid] = possum; s_f2[wid] = negsum; s_f3[wid] = locsum; s_i[wid] = cnt; }
    __syncthreads();
    float negsum_t = 0.0f, possum_t = 0.0f, locsum_t = 0.0f; int np = 0;
    #pragma unroll
    for (int w = 0; w < 16; ++w) {
        negsum_t += s_f2[w]; possum_t += s_f[w]; locsum_t += s_f3[w]; np += s_i[w];
    }
    if (tid == 0) { ce_pos[b] = possum_t; n_pos[b] = np; loc_b[b] = locsum_t; }

    const int K = 3 * np;
    if (K <= 0) { if (tid == 0) ce_hard[b] = 0.0f; return; }
    if (K >= P) { if (tid == 0) ce_hard[b] = negsum_t; return; }

    unsigned int prefix = 0; int kr = K;
    for (int shift = 24; shift >= 0; shift -= 8) {
        for (int i = tid; i < 16 * 256; i += 1024) (&hist[0][0])[i] = 0;
        __syncthreads();
        unsigned int maskHi = (shift == 24) ? 0u : (0xFFFFFFFFu << (shift + 8));
        for (int p = tid; p < P; p += 1024) {
            unsigned int u = __float_as_uint(s_v[p]);
            if ((u & maskHi) == prefix) atomicAdd(&hist[wid][(u >> shift) & 255], 1u);
        }
        __syncthreads();
        if (wid == 0) {
            unsigned h0 = 0, h1 = 0, h2 = 0, h3 = 0;
            #pragma unroll 4
            for (int w = 0; w < 16; ++w) {
                h0 += hist[w][lane * 4 + 0];
                h1 += hist[w][lane * 4 + 1];
                h2 += hist[w][lane * 4 + 2];
                h3 += hist[w][lane * 4 + 3];
            }
            unsigned own = h0 + h1 + h2 + h3;
            unsigned t = own;                    // inclusive suffix over lanes
            #pragma unroll
            for (int off = 1; off < 64; off <<= 1) {
                unsigned u = __shfl_down(t, off);
                if (lane + off >= 64) u = 0;
                t += u;
            }
            unsigned Tnext = t - own;            // strictly-higher lanes
            unsigned cum3 = Tnext;
            unsigned cum2 = cum3 + h3;
            unsigned cum1 = cum2 + h2;
            unsigned cum0 = cum1 + h1;
            unsigned kru = (unsigned)kr;
            int selj = -1; unsigned cg = 0;
            if      (cum3 < kru && kru <= cum3 + h3) { selj = 3; cg = cum3; }
            else if (cum2 < kru && kru <= cum2 + h2) { selj = 2; cg = cum2; }
            else if (cum1 < kru && kru <= cum1 + h1) { selj = 1; cg = cum1; }
            else if (cum0 < kru && kru <= cum0 + h0) { selj = 0; cg = cum0; }
            if (selj >= 0) {
                s_sel = prefix | ((unsigned)(lane * 4 + selj) << shift);
                s_kr  = kr - (int)cg;
            }
        }
        __syncthreads();
        prefix = s_sel; kr = s_kr;
        __syncthreads();
    }

    float sumgt = 0.0f;
    for (int p = tid; p < P; p += 1024) {
        unsigned int u = __float_as_uint(s_v[p]);
        if (u > prefix) sumgt += s_v[p];
    }
    sumgt = waveSumF(sumgt);
    if (lane == 0) s_f[wid] = sumgt;
    __syncthreads();
    if (tid == 0) {
        float sg = 0.0f;
        #pragma unroll
        for (int w = 0; w < 16; ++w) sg += s_f[w];
        ce_hard[b] = sg + (float)kr * __uint_as_float(prefix);
    }
}

// ---------------------------------------------------------------------------
// K3: finalize scalar loss. One wave, deterministic fixed-order sums.
// ---------------------------------------------------------------------------
__global__ __launch_bounds__(64) void finalize_kernel(
    const int*   __restrict__ n_pos,    // [B]
    const float* __restrict__ ce_pos,   // [B]
    const float* __restrict__ ce_hard,  // [B]
    const float* __restrict__ loc_b,    // [B]
    float* __restrict__ out, int B)
{
    const int lane = threadIdx.x;
    int np = 0; float cp = 0.0f, ch = 0.0f, la = 0.0f;
    for (int b = lane; b < B; b += 64) {
        np += n_pos[b]; cp += ce_pos[b]; ch += ce_hard[b]; la += loc_b[b];
    }
    #pragma unroll
    for (int off = 32; off; off >>= 1) {
        np += __shfl_xor(np, off);
        cp += __shfl_xor(cp, off);
        ch += __shfl_xor(ch, off);
        la += __shfl_xor(la, off);
    }
    if (lane == 0) {
        float npt = (float)np;
        out[0] = (ch + cp) / npt + la / (npt * 4.0f);
    }
}

extern "C" void kernel_launch(void* const* d_in, const int* in_sizes, int n_in,
                              void* d_out, int out_size, void* d_ws, size_t ws_size,
                              hipStream_t stream) {
    const float* predict_locs  = (const float*)d_in[0];
    const float* predict_confs = (const float*)d_in[1];
    const float* target_boxes  = (const float*)d_in[2];
    const int*   target_labels = (const int*)d_in[3];
    const float* priors        = (const float*)d_in[4];

    const int P = in_sizes[4] / 4;             // 8732
    const int B = in_sizes[0] / (P * 4);       // 64
    const int rows = B * P;                    // 558848
    const int ntile = rows / 64;               // 8732
    const int nmatch = B * CH;                 // 256

    char* ws = (char*)d_ws;
    unsigned long long* okey_part = (unsigned long long*)ws;
    ws += (size_t)nmatch * O_C * sizeof(unsigned long long);
    float* lse     = (float*)ws; ws += (size_t)rows * sizeof(float);
    int*   n_pos   = (int*)ws;   ws += (size_t)B * sizeof(int);
    float* ce_pos  = (float*)ws; ws += (size_t)B * sizeof(float);
    float* ce_hard = (float*)ws; ws += (size_t)B * sizeof(float);
    float* loc_b   = (float*)ws; ws += (size_t)B * sizeof(float);

    lse_match<<<nmatch + NCE, 256, 0, stream>>>(
        predict_confs, target_boxes, priors, okey_part, lse, P, ntile, nmatch);
    hard_kernel<<<B, 1024, 0, stream>>>(
        predict_confs, lse, okey_part, target_boxes, target_labels,
        priors, predict_locs, n_pos, ce_pos, ce_hard, loc_b, P);
    finalize_kernel<<<1, 64, 0, stream>>>(n_pos, ce_pos, ce_hard, loc_b,
                                          (float*)d_out, B);
}